// Round 1
// baseline (1414.673 us; speedup 1.0000x reference)
//
#include <hip/hip_runtime.h>

// ---------------------------------------------------------------------------
// GIN (5 layers) + BN + graph pooling + 2-layer MLP head, fp32.
// Strategy:
//   - Build dst-CSR once per call (histogram -> scan -> fill).
//   - y = x @ W1a  (so layer 1 aggregates in 64-dim like all others).
//   - Per layer: wave-per-node; lane = channel. s = v_i + sum_j v_j (gather,
//     coalesced 256B per neighbor). BN of previous layer folded as affine
//     (a,b):  h2 = a*s + b*(1+deg).  Two 64x64 matvecs via LDS.
//   - BN stats (sum, sumsq) accumulated per wave, atomically merged; tiny
//     kernel computes a = gamma*rsqrt(var+eps), b = beta - mu*a.
//   - pooled[g] = a*S[g] + b*cnt[g] where S = per-graph sum of raw v.
//   - Final head: wave-per-graph, z (320) in LDS, fc1/fc2 + wave reduction.
// ---------------------------------------------------------------------------

#define SCAN_ELEMS 1024

__global__ __launch_bounds__(256) void k_hist(const int* __restrict__ dst, int E,
        int* __restrict__ cnt_node, const int* __restrict__ batch, int N,
        int* __restrict__ cnt_graph) {
    int i = blockIdx.x * blockDim.x + threadIdx.x;
    if (i < E) atomicAdd(&cnt_node[dst[i]], 1);
    if (i < N) atomicAdd(&cnt_graph[batch[i]], 1);
}

__global__ __launch_bounds__(256) void k_scan1(const int* __restrict__ cnt, int n,
        int* __restrict__ rp, int* __restrict__ bsum) {
    __shared__ int sdata[256];
    int t = threadIdx.x;
    int base = blockIdx.x * SCAN_ELEMS + t * 4;
    int v0 = (base + 0 < n) ? cnt[base + 0] : 0;
    int v1 = (base + 1 < n) ? cnt[base + 1] : 0;
    int v2 = (base + 2 < n) ? cnt[base + 2] : 0;
    int v3 = (base + 3 < n) ? cnt[base + 3] : 0;
    int tsum = v0 + v1 + v2 + v3;
    sdata[t] = tsum;
    __syncthreads();
    for (int off = 1; off < 256; off <<= 1) {
        int val = (t >= off) ? sdata[t - off] : 0;
        __syncthreads();
        sdata[t] += val;
        __syncthreads();
    }
    int excl = sdata[t] - tsum;
    if (t == 255) bsum[blockIdx.x] = sdata[255];
    if (base + 0 < n) rp[base + 0] = excl;
    if (base + 1 < n) rp[base + 1] = excl + v0;
    if (base + 2 < n) rp[base + 2] = excl + v0 + v1;
    if (base + 3 < n) rp[base + 3] = excl + v0 + v1 + v2;
}

__global__ __launch_bounds__(128) void k_scan2(const int* __restrict__ bsum, int nb,
        int* __restrict__ boffs) {
    __shared__ int sd[128];
    int t = threadIdx.x;
    int v = (t < nb) ? bsum[t] : 0;
    sd[t] = v;
    __syncthreads();
    for (int off = 1; off < 128; off <<= 1) {
        int val = (t >= off) ? sd[t - off] : 0;
        __syncthreads();
        sd[t] += val;
        __syncthreads();
    }
    if (t < nb) boffs[t] = sd[t] - v;
}

__global__ __launch_bounds__(256) void k_scan3(int* __restrict__ rp, int n,
        const int* __restrict__ boffs, int E) {
    int i = blockIdx.x * blockDim.x + threadIdx.x;
    if (i < n) rp[i] += boffs[i / SCAN_ELEMS];
    if (i == 0) rp[n] = E;
}

__global__ __launch_bounds__(256) void k_fill(const int* __restrict__ src,
        const int* __restrict__ dst, int E, const int* __restrict__ rp,
        int* __restrict__ cursor, int* __restrict__ col) {
    int e = blockIdx.x * blockDim.x + threadIdx.x;
    if (e < E) {
        int d = dst[e];
        int pos = rp[d] + atomicAdd(&cursor[d], 1);
        col[pos] = src[e];
    }
}

// y = x @ W1a   (x: [N,11], W1a: [11,64])
__global__ __launch_bounds__(256) void k_premm(const float* __restrict__ x,
        const float* __restrict__ W1a, float* __restrict__ y, int N) {
    __shared__ float lw[11 * 64];
    int tid = threadIdx.x;
    for (int i = tid; i < 11 * 64; i += 256) lw[i] = W1a[i];
    __syncthreads();
    int lane = tid & 63, wv = tid >> 6;
    int wg = blockIdx.x * 4 + wv, ws = gridDim.x * 4;
    for (int i = wg; i < N; i += ws) {
        float xv = (lane < 11) ? x[i * 11 + lane] : 0.f;
        float acc = 0.f;
#pragma unroll
        for (int k = 0; k < 11; ++k) {
            float xk = __shfl(xv, k);
            acc += xk * lw[k * 64 + lane];
        }
        y[i * 64 + lane] = acc;
    }
}

// One GIN layer. FIRST: t = relu(s + ba) (the @W1a already folded into vin);
// else: h2 = a*s + b*(1+deg), t = relu(h2@Wa + ba).  Then v = relu(t@Wb + bb).
// Emits: vout, per-graph sums of v (Sg), per-channel sum/sumsq (bn stats).
template <bool FIRST>
__global__ __launch_bounds__(256) void k_layer(
        const float* __restrict__ vin, float* __restrict__ vout,
        const int* __restrict__ rp, const int* __restrict__ col,
        const int* __restrict__ batch,
        const float* __restrict__ a_prev, const float* __restrict__ b_prev,
        const float* __restrict__ Wa, const float* __restrict__ ba,
        const float* __restrict__ Wb, const float* __restrict__ bb,
        float* __restrict__ Sg, float* __restrict__ bnsum, float* __restrict__ bnsq,
        int N) {
    __shared__ float lwa[64 * 64];
    __shared__ float lwb[64 * 64];
    __shared__ float hbuf[4][64];
    __shared__ float tbuf[4][64];
    int tid = threadIdx.x;
    if (!FIRST) {
        for (int i = tid; i < 4096; i += 256) lwa[i] = Wa[i];
    }
    for (int i = tid; i < 4096; i += 256) lwb[i] = Wb[i];
    __syncthreads();

    int lane = tid & 63, wv = tid >> 6;
    float ac = FIRST ? 1.f : a_prev[lane];
    float bc = FIRST ? 0.f : b_prev[lane];
    float bac = ba[lane], bbc = bb[lane];
    float bsum = 0.f, bsq = 0.f;

    int total_waves = gridDim.x * 4;
    int wglobal = blockIdx.x * 4 + wv;
    int chunk = (N + total_waves - 1) / total_waves;
    int i0 = wglobal * chunk;
    int i1 = i0 + chunk; if (i1 > N) i1 = N;

    int curg = -1;
    float pacc = 0.f;
    for (int i = i0; i < i1; ++i) {
        int start = rp[i], end = rp[i + 1];
        float s0 = vin[i * 64 + lane], s1 = 0.f;
        for (int base = start; base < end; base += 64) {
            int e = base + lane;
            int j = (e < end) ? col[e] : 0;
            int m = end - base; if (m > 64) m = 64;
            int k = 0;
            for (; k + 1 < m; k += 2) {
                int j0 = __shfl(j, k);
                int j1 = __shfl(j, k + 1);
                s0 += vin[j0 * 64 + lane];
                s1 += vin[j1 * 64 + lane];
            }
            if (k < m) {
                int j0 = __shfl(j, k);
                s0 += vin[j0 * 64 + lane];
            }
        }
        float s = s0 + s1;
        float t;
        if (FIRST) {
            t = fmaxf(s + bac, 0.f);
        } else {
            float h2 = ac * s + bc * (float)(1 + end - start);
            hbuf[wv][lane] = h2;
            float acc = bac;
#pragma unroll 8
            for (int k = 0; k < 64; ++k) acc += hbuf[wv][k] * lwa[k * 64 + lane];
            t = fmaxf(acc, 0.f);
        }
        tbuf[wv][lane] = t;
        float acc2 = bbc;
#pragma unroll 8
        for (int k = 0; k < 64; ++k) acc2 += tbuf[wv][k] * lwb[k * 64 + lane];
        float v = fmaxf(acc2, 0.f);
        vout[i * 64 + lane] = v;
        bsum += v; bsq += v * v;
        int g = batch[i];
        if (g != curg) {
            if (curg >= 0) atomicAdd(&Sg[curg * 64 + lane], pacc);
            curg = g; pacc = 0.f;
        }
        pacc += v;
    }
    if (curg >= 0) atomicAdd(&Sg[curg * 64 + lane], pacc);
    atomicAdd(&bnsum[lane], bsum);
    atomicAdd(&bnsq[lane], bsq);
}

__global__ void k_bnstat(const float* __restrict__ bnsum, const float* __restrict__ bnsq,
        const float* __restrict__ gamma, const float* __restrict__ beta,
        float* __restrict__ a, float* __restrict__ b, int N) {
    int c = threadIdx.x;  // 64 threads
    float invN = 1.0f / (float)N;
    float mu = bnsum[c] * invN;
    float var = bnsq[c] * invN - mu * mu;
    float ac = gamma[c] * rsqrtf(var + 1e-5f);
    a[c] = ac;
    b[c] = beta[c] - mu * ac;
}

// Head: z[g,320] = concat_l (a_l*S_l[g] + b_l*cnt[g]); out = relu(z@fc1+b)@fc2+b
__global__ __launch_bounds__(256) void k_final(
        const float* __restrict__ S, const float* __restrict__ ab,
        const int* __restrict__ cntg,
        const float* __restrict__ fc1W, const float* __restrict__ fc1b,
        const float* __restrict__ fc2W, const float* __restrict__ fc2b,
        float* __restrict__ out, int G) {
    __shared__ float zbuf[4][320];
    int tid = threadIdx.x;
    int lane = tid & 63, wv = tid >> 6;
    int g = blockIdx.x * 4 + wv;
    if (g >= G) return;
    float cf = (float)cntg[g];
#pragma unroll
    for (int l = 0; l < 5; ++l) {
        float a = ab[l * 128 + lane];
        float b = ab[l * 128 + 64 + lane];
        zbuf[wv][l * 64 + lane] = a * S[((size_t)l * G + g) * 64 + lane] + b * cf;
    }
    float acc = fc1b[lane];
    for (int k = 0; k < 320; ++k) acc += zbuf[wv][k] * fc1W[k * 64 + lane];
    float t = fmaxf(acc, 0.f);
    float r = t * fc2W[lane];
#pragma unroll
    for (int off = 32; off >= 1; off >>= 1) r += __shfl_xor(r, off);
    if (lane == 0) out[g] = r + fc2b[0];
}

extern "C" void kernel_launch(void* const* d_in, const int* in_sizes, int n_in,
                              void* d_out, int out_size, void* d_ws, size_t ws_size,
                              hipStream_t stream) {
    const float* x    = (const float*)d_in[0];
    const int*   ei   = (const int*)d_in[1];
    const int*   batch= (const int*)d_in[2];
    const float* W1a  = (const float*)d_in[3];
    const float* b1a  = (const float*)d_in[4];
    const float* W1b  = (const float*)d_in[5];
    const float* b1b  = (const float*)d_in[6];
    const float* Wa   = (const float*)d_in[7];
    const float* ba   = (const float*)d_in[8];
    const float* Wb   = (const float*)d_in[9];
    const float* bb   = (const float*)d_in[10];
    const float* gamma= (const float*)d_in[11];
    const float* beta = (const float*)d_in[12];
    const float* fc1W = (const float*)d_in[13];
    const float* fc1b = (const float*)d_in[14];
    const float* fc2W = (const float*)d_in[15];
    const float* fc2b = (const float*)d_in[16];

    const int N = in_sizes[2];
    const int E = in_sizes[1] / 2;
    const int G = out_size;
    const int* srcp = ei;
    const int* dstp = ei + E;

    char* p = (char*)d_ws;
    auto alloc = [&](size_t bytes) {
        char* r = p;
        p += (bytes + 255) & ~size_t(255);
        return r;
    };
    float* B0     = (float*)alloc((size_t)N * 64 * 4);
    float* B1     = (float*)alloc((size_t)N * 64 * 4);
    int*   col    = (int*)  alloc((size_t)E * 4);
    int*   rp     = (int*)  alloc((size_t)(N + 1) * 4);
    int*   cntn   = (int*)  alloc((size_t)N * 4);
    int*   cursor = (int*)  alloc((size_t)N * 4);
    int*   bsum   = (int*)  alloc(512);
    int*   boffs  = (int*)  alloc(512);
    int*   cntg   = (int*)  alloc((size_t)G * 4);
    float* S      = (float*)alloc((size_t)5 * G * 64 * 4);
    float* bnbuf  = (float*)alloc(5 * 128 * 4);
    float* ab     = (float*)alloc(5 * 128 * 4);

    hipMemsetAsync(cntn,   0, (size_t)N * 4, stream);
    hipMemsetAsync(cursor, 0, (size_t)N * 4, stream);
    hipMemsetAsync(cntg,   0, (size_t)G * 4, stream);
    hipMemsetAsync(S,      0, (size_t)5 * G * 64 * 4, stream);
    hipMemsetAsync(bnbuf,  0, 5 * 128 * 4, stream);

    int nb_e = (E + 255) / 256;
    int nb_scan = (N + SCAN_ELEMS - 1) / SCAN_ELEMS;
    k_hist<<<nb_e, 256, 0, stream>>>(dstp, E, cntn, batch, N, cntg);
    k_scan1<<<nb_scan, 256, 0, stream>>>(cntn, N, rp, bsum);
    k_scan2<<<1, 128, 0, stream>>>(bsum, nb_scan, boffs);
    k_scan3<<<(N + 255) / 256, 256, 0, stream>>>(rp, N, boffs, E);
    k_fill<<<nb_e, 256, 0, stream>>>(srcp, dstp, E, rp, cursor, col);

    k_premm<<<1024, 256, 0, stream>>>(x, W1a, B0, N);

    // Layer 1 (weights folded: vin = x@W1a)
    k_layer<true><<<1024, 256, 0, stream>>>(B0, B1, rp, col, batch,
        nullptr, nullptr, nullptr, b1a, W1b, b1b,
        S, bnbuf, bnbuf + 64, N);
    k_bnstat<<<1, 64, 0, stream>>>(bnbuf, bnbuf + 64, gamma, beta, ab, ab + 64, N);

    const float* vin = B1;
    float* vout = B0;
    for (int l = 0; l < 4; ++l) {
        k_layer<false><<<1024, 256, 0, stream>>>(vin, vout, rp, col, batch,
            ab + l * 128, ab + l * 128 + 64,
            Wa + l * 4096, ba + l * 64, Wb + l * 4096, bb + l * 64,
            S + (size_t)(l + 1) * G * 64,
            bnbuf + (l + 1) * 128, bnbuf + (l + 1) * 128 + 64, N);
        k_bnstat<<<1, 64, 0, stream>>>(
            bnbuf + (l + 1) * 128, bnbuf + (l + 1) * 128 + 64,
            gamma + (l + 1) * 64, beta + (l + 1) * 64,
            ab + (l + 1) * 128, ab + (l + 1) * 128 + 64, N);
        float* t = vout; vout = (float*)vin; vin = t;
    }

    k_final<<<(G + 3) / 4, 256, 0, stream>>>(S, ab, cntg, fc1W, fc1b, fc2W, fc2b,
                                             (float*)d_out, G);
}